// Round 1
// baseline (480.078 us; speedup 1.0000x reference)
//
#include <hip/hip_runtime.h>
#include <hip/hip_bf16.h>
#include <stddef.h>

// Problem dims
#define BB 64
#define TTOT 64
#define EE 64
#define HH 128
#define G4 512          // 4*H
#define VIN 256
#define VOUT 32000

typedef __attribute__((ext_vector_type(8))) short bf16x8;
typedef __attribute__((ext_vector_type(4))) float f32x4;

__device__ __forceinline__ unsigned short f2bf(float x) {
    unsigned int u = __float_as_uint(x);
    unsigned int r = (u + 0x7fffu + ((u >> 16) & 1u)) >> 16;
    return (unsigned short)r;
}

__device__ __forceinline__ float fsig(float x) {
    return 1.f / (1.f + __expf(-x));
}
__device__ __forceinline__ float ftanh(float x) {
    // 1 - 2/(e^{2x}+1); saturates correctly at +/-1 for large |x|
    return 1.f - 2.f / (__expf(2.f * x) + 1.f);
}

// ---------------- fc_W fp32 -> bf16 ----------------
__global__ void conv_bf16(const float* __restrict__ in, unsigned short* __restrict__ out, int n) {
    for (int i = blockIdx.x * blockDim.x + threadIdx.x; i < n; i += gridDim.x * blockDim.x)
        out[i] = f2bf(in[i]);
}

// ---------------- encoder gate table: table[v][g] = emb[v]·Wih[g] + bih[g] ----------------
__global__ __launch_bounds__(512) void enc_table_k(const float* __restrict__ emb,
                                                   const float* __restrict__ Wih,
                                                   const float* __restrict__ bih,
                                                   float* __restrict__ table) {
    int v = blockIdx.x;
    int g = threadIdx.x;
    __shared__ __align__(16) float x[EE];
    if (g < EE) x[g] = (v == 0) ? 0.f : emb[(size_t)v * EE + g];
    __syncthreads();
    float acc = bih[g];
    const float* wr = Wih + (size_t)g * EE;
#pragma unroll
    for (int e = 0; e < EE; e += 4) {
        float4 w4 = *(const float4*)(wr + e);
        float4 x4 = *(const float4*)(&x[e]);
        acc = fmaf(x4.x, w4.x, acc);
        acc = fmaf(x4.y, w4.y, acc);
        acc = fmaf(x4.z, w4.z, acc);
        acc = fmaf(x4.w, w4.w, acc);
    }
    table[(size_t)v * G4 + g] = acc;
}

// ---------------- decoder input gates: xg[t*64+b][g] = dec_emb[tgt[b][t]]·Wih[g] + bih[g] ----------------
// 4 (t,b) pairs per block to amortize the Wih stream.
__global__ __launch_bounds__(512) void xg_dec_k(const int* __restrict__ tgt,
                                                const float* __restrict__ emb,
                                                const float* __restrict__ Wih,
                                                const float* __restrict__ bih,
                                                float* __restrict__ xg) {
    int p0 = blockIdx.x * 4;  // pair index = t*64 + b, t in [0,63)
    int g = threadIdx.x;
    __shared__ __align__(16) float x[4][EE];
    if (g < 4 * EE) {
        int pr = g >> 6, e = g & 63;
        int pair = p0 + pr;
        int t = pair >> 6, b = pair & 63;
        int tok = tgt[b * TTOT + t];
        x[pr][e] = (tok == 0) ? 0.f : emb[(size_t)tok * EE + e];
    }
    __syncthreads();
    float bi = bih[g];
    float acc0 = bi, acc1 = bi, acc2 = bi, acc3 = bi;
    const float* wr = Wih + (size_t)g * EE;
#pragma unroll
    for (int e = 0; e < EE; e += 4) {
        float4 w4 = *(const float4*)(wr + e);
#define STEP(pr, accv)                                        \
        {                                                     \
            float4 x4 = *(const float4*)(&x[pr][e]);          \
            accv = fmaf(x4.x, w4.x, accv);                    \
            accv = fmaf(x4.y, w4.y, accv);                    \
            accv = fmaf(x4.z, w4.z, accv);                    \
            accv = fmaf(x4.w, w4.w, accv);                    \
        }
        STEP(0, acc0) STEP(1, acc1) STEP(2, acc2) STEP(3, acc3)
#undef STEP
    }
    xg[(size_t)(p0 + 0) * G4 + g] = acc0;
    xg[(size_t)(p0 + 1) * G4 + g] = acc1;
    xg[(size_t)(p0 + 2) * G4 + g] = acc2;
    xg[(size_t)(p0 + 3) * G4 + g] = acc3;
}

// ---------------- encoder LSTM: one block per batch row ----------------
__global__ __launch_bounds__(512) void lstm_enc_k(const float* __restrict__ table,
                                                  const int* __restrict__ src,
                                                  const float* __restrict__ Whh,
                                                  const float* __restrict__ bhh,
                                                  float* __restrict__ hfin,
                                                  float* __restrict__ cfin) {
    int b = blockIdx.x, g = threadIdx.x;
    __shared__ __align__(16) float h[HH];
    __shared__ float gates[G4];
    __shared__ int toks[TTOT];

    float w[HH];
#pragma unroll
    for (int k = 0; k < HH; k += 4) {
        float4 t4 = *(const float4*)(Whh + (size_t)g * HH + k);
        w[k] = t4.x; w[k + 1] = t4.y; w[k + 2] = t4.z; w[k + 3] = t4.w;
    }
    if (g < TTOT) toks[g] = src[b * TTOT + g];
    if (g < HH) h[g] = 0.f;
    float c = 0.f;
    float bb = bhh[g];
    __syncthreads();

#pragma unroll 1
    for (int t = 0; t < TTOT; ++t) {
        int tok = toks[t];
        float acc = table[(size_t)tok * G4 + g] + bb;
#pragma unroll
        for (int k = 0; k < HH; k += 4) {
            float4 h4 = *(const float4*)(&h[k]);
            acc = fmaf(h4.x, w[k], acc);
            acc = fmaf(h4.y, w[k + 1], acc);
            acc = fmaf(h4.z, w[k + 2], acc);
            acc = fmaf(h4.w, w[k + 3], acc);
        }
        gates[g] = acc;
        __syncthreads();
        if (g < HH) {
            float fi = fsig(gates[g]);
            float ff = fsig(gates[HH + g]);
            float fg = ftanh(gates[2 * HH + g]);
            float fo = fsig(gates[3 * HH + g]);
            c = ff * c + fi * fg;
            h[g] = fo * ftanh(c);
        }
        __syncthreads();
    }
    if (g < HH) {
        hfin[(size_t)b * HH + g] = h[g];
        cfin[(size_t)b * HH + g] = c;
    }
}

// ---------------- decoder LSTM: one block per batch row, writes hs as bf16 ----------------
__global__ __launch_bounds__(512) void lstm_dec_k(const float* __restrict__ xg,
                                                  const float* __restrict__ Whh,
                                                  const float* __restrict__ bhh,
                                                  const float* __restrict__ h0,
                                                  const float* __restrict__ c0,
                                                  unsigned short* __restrict__ hs) {
    int b = blockIdx.x, g = threadIdx.x;
    __shared__ __align__(16) float h[HH];
    __shared__ float gates[G4];

    float w[HH];
#pragma unroll
    for (int k = 0; k < HH; k += 4) {
        float4 t4 = *(const float4*)(Whh + (size_t)g * HH + k);
        w[k] = t4.x; w[k + 1] = t4.y; w[k + 2] = t4.z; w[k + 3] = t4.w;
    }
    float c = 0.f;
    if (g < HH) {
        h[g] = h0[(size_t)b * HH + g];
        c = c0[(size_t)b * HH + g];
    }
    float bb = bhh[g];
    __syncthreads();

#pragma unroll 1
    for (int t = 0; t < TTOT - 1; ++t) {
        float acc = xg[((size_t)t * BB + b) * G4 + g] + bb;
#pragma unroll
        for (int k = 0; k < HH; k += 4) {
            float4 h4 = *(const float4*)(&h[k]);
            acc = fmaf(h4.x, w[k], acc);
            acc = fmaf(h4.y, w[k + 1], acc);
            acc = fmaf(h4.z, w[k + 2], acc);
            acc = fmaf(h4.w, w[k + 3], acc);
        }
        gates[g] = acc;
        __syncthreads();
        if (g < HH) {
            float fi = fsig(gates[g]);
            float ff = fsig(gates[HH + g]);
            float fg = ftanh(gates[2 * HH + g]);
            float fo = fsig(gates[3 * HH + g]);
            c = ff * c + fi * fg;
            float hn = fo * ftanh(c);
            h[g] = hn;
            hs[((size_t)t * BB + b) * HH + g] = f2bf(hn);
        }
        __syncthreads();
    }
}

// ---------------- zero out[:, 0, :] ----------------
__global__ void zero_t0_k(float* __restrict__ out) {
    int b = blockIdx.x;
    float4* p = (float4*)(out + (size_t)b * TTOT * VOUT);
    float4 z = make_float4(0.f, 0.f, 0.f, 0.f);
    for (int i = threadIdx.x; i < VOUT / 4; i += blockDim.x) p[i] = z;
}

// ---------------- FC head: out[b][t+1][n] = hs[t][b]·fc_W[n] + fc_b[n] ----------------
// grid (63, 250): x = t (fast, so concurrent blocks share the fc_W tile in L2), y = n-tile.
// 4 waves, each one 16-row band of the 64-row tile; 8 n-subtiles of 16; K=128 = 4 MFMA k-steps.
__global__ __launch_bounds__(256) void fc_k(const unsigned short* __restrict__ hs,
                                            const unsigned short* __restrict__ fw,
                                            const float* __restrict__ fb,
                                            float* __restrict__ out) {
    int t = blockIdx.x;
    int nt0 = blockIdx.y * 128;
    int wave = threadIdx.x >> 6;
    int lane = threadIdx.x & 63;
    int l15 = lane & 15;
    int kg = lane >> 4;  // k-group 0..3

    // A fragments: A[M=lane&15][K = kt*32 + kg*8 + j]
    const unsigned short* arow = hs + ((size_t)t * BB + wave * 16 + l15) * HH + kg * 8;
    bf16x8 a[4];
#pragma unroll
    for (int kt = 0; kt < 4; ++kt) a[kt] = *(const bf16x8*)(arow + kt * 32);

    f32x4 acc[8];
#pragma unroll
    for (int nt = 0; nt < 8; ++nt) acc[nt] = (f32x4){0.f, 0.f, 0.f, 0.f};

#pragma unroll
    for (int nt = 0; nt < 8; ++nt) {
        const unsigned short* brow = fw + ((size_t)nt0 + nt * 16 + l15) * HH + kg * 8;
#pragma unroll
        for (int kt = 0; kt < 4; ++kt) {
            bf16x8 bf = *(const bf16x8*)(brow + kt * 32);
            acc[nt] = __builtin_amdgcn_mfma_f32_16x16x32_bf16(a[kt], bf, acc[nt], 0, 0, 0);
        }
    }

#pragma unroll
    for (int nt = 0; nt < 8; ++nt) {
        int n = nt0 + nt * 16 + l15;
        float bias = fb[n];
#pragma unroll
        for (int j = 0; j < 4; ++j) {
            int brow_idx = wave * 16 + kg * 4 + j;  // batch row within tile (M index)
            out[((size_t)brow_idx * TTOT + (t + 1)) * VOUT + n] = acc[nt][j] + bias;
        }
    }
}

extern "C" void kernel_launch(void* const* d_in, const int* in_sizes, int n_in,
                              void* d_out, int out_size, void* d_ws, size_t ws_size,
                              hipStream_t stream) {
    const int* src = (const int*)d_in[0];
    const int* tgt = (const int*)d_in[1];
    const float* enc_emb = (const float*)d_in[2];
    const float* dec_emb = (const float*)d_in[3];
    const float* enc_Wih = (const float*)d_in[4];
    const float* enc_Whh = (const float*)d_in[5];
    const float* enc_bih = (const float*)d_in[6];
    const float* enc_bhh = (const float*)d_in[7];
    const float* dec_Wih = (const float*)d_in[8];
    const float* dec_Whh = (const float*)d_in[9];
    const float* dec_bih = (const float*)d_in[10];
    const float* dec_bhh = (const float*)d_in[11];
    const float* fc_W = (const float*)d_in[12];
    const float* fc_b = (const float*)d_in[13];
    float* out = (float*)d_out;
    char* ws = (char*)d_ws;

    // workspace layout (bytes)
    float* table = (float*)(ws + 0);                        // 256*512*4   = 524288
    float* hfin = (float*)(ws + 524288);                    // 64*128*4    = 32768
    float* cfin = (float*)(ws + 557056);                    // 64*128*4    = 32768
    unsigned short* hs = (unsigned short*)(ws + 589824);    // 63*64*128*2 = 1032192
    unsigned short* fwb = (unsigned short*)(ws + 1622016);  // 32000*128*2 = 8192000
    float* xgd = (float*)(ws + 9814016);                    // 63*64*512*4 = 8257536
    // total 18071552 bytes

    conv_bf16<<<2048, 256, 0, stream>>>(fc_W, fwb, VOUT * HH);
    enc_table_k<<<VIN, 512, 0, stream>>>(enc_emb, enc_Wih, enc_bih, table);
    xg_dec_k<<<(63 * 64) / 4, 512, 0, stream>>>(tgt, dec_emb, dec_Wih, dec_bih, xgd);
    lstm_enc_k<<<BB, 512, 0, stream>>>(table, src, enc_Whh, enc_bhh, hfin, cfin);
    lstm_dec_k<<<BB, 512, 0, stream>>>(xgd, dec_Whh, dec_bhh, hfin, cfin, hs);
    zero_t0_k<<<BB, 256, 0, stream>>>(out);
    fc_k<<<dim3(63, 250), 256, 0, stream>>>(hs, fwb, fc_b, out);
}